// Round 13
// baseline (71.232 us; speedup 1.0000x reference)
//
#include <hip/hip_runtime.h>

#define EDIM 255   // tree node count (complete binary tree, 8 levels)
#define EPAD 256   // bf16 slots per row (512 B)

// LDS-only fence: compiler barrier + lgkmcnt(0), NO vmcnt drain
// (prefetched global loads stay in flight across the tree ladder).
#define LDS_FENCE() do { \
    asm volatile("s_waitcnt lgkmcnt(0)" ::: "memory"); \
    __builtin_amdgcn_sched_barrier(0); \
} while (0)

__device__ __forceinline__ float wave_reduce_sum(float v) {
    #pragma unroll
    for (int off = 32; off > 0; off >>= 1) v += __shfl_xor(v, off, 64);
    return v;
}
__device__ __forceinline__ float wave_reduce_max(float v) {
    #pragma unroll
    for (int off = 32; off > 0; off >>= 1) v = fmaxf(v, __shfl_xor(v, off, 64));
    return v;
}

// ---------------- Phase 1: per-row transform -> bf16 table -----------------
// delta[r][slot(e)] = (tree_subtree_sum(softmax(emb[r]))[e] - s_e/255) * w[e]
// stored bf16 rne, NO scale (r12-proven: coherent L1 quant error ~1e-6 ok).
// slot(e)=4*(e&63)+(e>>6): one 8B store/lane. Phase 2 is elementwise over
// slots -> any fixed permutation valid. No max-subtract (|emb|<=0.001, r8+).
// Structure: grid-stride, 1 row/wave, next-row prefetch held across the
// ladder (LDS_FENCE never drains vmcnt). Tree at Q[e+1] so ladder children
// are an aligned ds_read_b64 pair. Levels cnt=64..8 in LDS (4 fences);
// top 3 levels (nodes 0..6) via r7-validated replicated shuffle folds
// (saves 3 near-serial drains). 6 fences/row total vs 9 in r9.
__global__ __launch_bounds__(256) void row_transform_b_kernel(
    const float* __restrict__ emb, const float* __restrict__ w,
    unsigned short* __restrict__ tq, int n_rows)
{
    __shared__ __align__(16) float sm[4][264];   // [wave][1+256+pad]
    const int lane   = threadIdx.x & 63;
    const int wv     = threadIdx.x >> 6;
    const int nwaves = gridDim.x * 4;
    float* Q = sm[wv];

    // row-invariant per-(lane,j) constants
    float wreg[4], base[4];
    #pragma unroll
    for (int j = 0; j < 4; ++j) {
        const int e = 64 * j + lane;
        if (e < EDIM) {
            wreg[j] = w[e];
            const int lvl = 31 - __clz(e + 1);              // floor(log2(e+1))
            base[j] = (float)((256 >> lvl) - 1) * (1.0f / 255.0f);
        } else { wreg[j] = 0.f; base[j] = 0.f; }
    }

    int r = blockIdx.x * 4 + wv;
    if (r >= n_rows) return;                 // wave-uniform; no barriers used

    float v[4];
    {
        const float* row = emb + (size_t)r * EDIM;
        #pragma unroll
        for (int j = 0; j < 4; ++j) {
            const int e = 64 * j + lane;                    // coalesced dwords
            v[j] = (e < EDIM) ? row[e] : -1e30f;            // exp -> 0 pad
        }
    }

    while (true) {
        // ---- prefetch next row (stays in flight through the ladder) ----
        const int  rn   = r + nwaves;
        const bool more = rn < n_rows;
        float vn[4];
        if (more) {
            const float* rown = emb + (size_t)rn * EDIM;
            #pragma unroll
            for (int j = 0; j < 4; ++j) {
                const int e = 64 * j + lane;
                vn[j] = (e < EDIM) ? rown[e] : -1e30f;
            }
        }

        // ---- softmax (no max-subtract) ----
        float pexp[4], s = 0.f;
        #pragma unroll
        for (int j = 0; j < 4; ++j) { pexp[j] = __expf(v[j]); s += pexp[j]; }
        s = wave_reduce_sum(s);
        const float is = 1.0f / s;
        #pragma unroll
        for (int j = 0; j < 4; ++j) Q[1 + 64 * j + lane] = pexp[j] * is;
        LDS_FENCE();

        // ---- ladder levels cnt=64,32,16,8 (nodes 7..126 finalized) ----
        #pragma unroll
        for (int cnt = 64; cnt >= 8; cnt >>= 1) {
            if (lane < cnt) {
                const int q = (cnt - 1) + lane;
                const float2 c = *(const float2*)&Q[2 * q + 2]; // aligned b64
                Q[q + 1] += c.x + c.y;
            }
            LDS_FENCE();
        }

        // ---- top 3 levels via replicated shuffle folds (r7-validated) ----
        // lane l holds t3 of node 7+(l>>3) (broadcast read, conflict-free)
        float t = Q[8 + (lane >> 3)];
        t = Q[4 + (lane >> 4)] + t + __shfl_xor(t, 8, 64);   // t2: nodes 3..6
        const float t2 = t;
        t = Q[2 + (lane >> 5)] + t + __shfl_xor(t, 16, 64);  // t1: nodes 1,2
        const float t1 = t;
        t = Q[1] + t + __shfl_xor(t, 32, 64);                // t0: node 0
        // masked writebacks (per-thread read->write deps keep order safe)
        if (!(lane & 15)) Q[4 + (lane >> 4)] = t2;
        if (!(lane & 31)) Q[2 + (lane >> 5)] = t1;
        if (lane == 0)    Q[1] = t;
        LDS_FENCE();

        // ---- epilogue: baseline-subtract, weight, bf16 rne pack ----
        unsigned pk0 = 0, pk1 = 0;
        #pragma unroll
        for (int j = 0; j < 4; ++j) {
            const float d = (Q[1 + 64 * j + lane] - base[j]) * wreg[j];
            unsigned u = __float_as_uint(d);
            u += 0x7fffu + ((u >> 16) & 1u);                 // bf16 rne
            const unsigned h = u >> 16;
            if (j == 0) pk0 = h;
            else if (j == 1) pk0 |= h << 16;
            else if (j == 2) pk1 = h;
            else pk1 |= h << 16;
        }
        uint2 pk; pk.x = pk0; pk.y = pk1;
        ((uint2*)(tq + (size_t)r * EPAD))[lane] = pk;        // one 8B store

        if (!more) break;
        r = rn;
        #pragma unroll
        for (int j = 0; j < 4; ++j) v[j] = vn[j];
        // next-iter Q-init writes hit the same per-lane slots the epilogue
        // just read -> per-thread dep; ladder is behind LDS_FENCE.
    }
}

// ---------------- Phase 2: per-pair L1 of bf16 rows ------------------------
// Grid-stride + one-pair-ahead prefetch (r12 bit-identical, passing).
__global__ __launch_bounds__(256) void pair_score_b_kernel(
    const int* __restrict__ x, const int* __restrict__ y,
    const unsigned short* __restrict__ tq, float* __restrict__ out, int n_pairs)
{
    const int lane   = threadIdx.x & 63;
    const int wv     = threadIdx.x >> 6;
    const int nwaves = gridDim.x * 4;

    int p = blockIdx.x * 4 + wv;
    if (p >= n_pairs) return;              // wave-uniform

    uint2 va = ((const uint2*)(tq + (size_t)x[p] * EPAD))[lane];
    uint2 vb = ((const uint2*)(tq + (size_t)y[p] * EPAD))[lane];

    while (true) {
        const int  pn   = p + nwaves;
        const bool more = pn < n_pairs;
        uint2 van = make_uint2(0u, 0u), vbn = van;
        if (more) {                        // prefetch next pair
            van = ((const uint2*)(tq + (size_t)x[pn] * EPAD))[lane];
            vbn = ((const uint2*)(tq + (size_t)y[pn] * EPAD))[lane];
        }

        const float a0 = __uint_as_float(va.x << 16);
        const float a1 = __uint_as_float(va.x & 0xffff0000u);
        const float a2 = __uint_as_float(va.y << 16);
        const float a3 = __uint_as_float(va.y & 0xffff0000u);
        const float b0 = __uint_as_float(vb.x << 16);
        const float b1 = __uint_as_float(vb.x & 0xffff0000u);
        const float b2 = __uint_as_float(vb.y << 16);
        const float b3 = __uint_as_float(vb.y & 0xffff0000u);
        float s = fabsf(a0 - b0) + fabsf(a1 - b1)
                + fabsf(a2 - b2) + fabsf(a3 - b3);
        s = wave_reduce_sum(s);
        if (lane == 0) out[p] = -s;

        if (!more) break;
        p = pn; va = van; vb = vbn;
    }
}

// ---------------- Fallback: round-1 fused kernel (if ws too small) ---------
__global__ __launch_bounds__(256) void treewe_score_kernel(
    const int* __restrict__ x, const int* __restrict__ y,
    const float* __restrict__ emb, const float* __restrict__ w,
    float* __restrict__ out, int n_pairs)
{
    __shared__ float sm[4][EPAD];
    const int lane = threadIdx.x & 63;
    const int wv   = threadIdx.x >> 6;
    const int p    = blockIdx.x * 4 + wv;
    const bool active = p < n_pairs;

    if (active) {
        const float* rowx = emb + (size_t)x[p] * EDIM;
        const float* rowy = emb + (size_t)y[p] * EDIM;
        float vx[4], vy[4];
        #pragma unroll
        for (int j = 0; j < 4; ++j) {
            const int e = 64 * j + lane;
            const bool in = (e < EDIM);
            vx[j] = in ? rowx[e] : -1e30f;
            vy[j] = in ? rowy[e] : -1e30f;
        }
        float mx = wave_reduce_max(fmaxf(fmaxf(vx[0], vx[1]), fmaxf(vx[2], vx[3])));
        float ex[4], sx = 0.f;
        #pragma unroll
        for (int j = 0; j < 4; ++j) { ex[j] = __expf(vx[j] - mx); sx += ex[j]; }
        sx = wave_reduce_sum(sx);
        float my = wave_reduce_max(fmaxf(fmaxf(vy[0], vy[1]), fmaxf(vy[2], vy[3])));
        float ey[4], sy = 0.f;
        #pragma unroll
        for (int j = 0; j < 4; ++j) { ey[j] = __expf(vy[j] - my); sy += ey[j]; }
        sy = wave_reduce_sum(sy);
        const float ixs = 1.0f / sx, iys = 1.0f / sy;
        #pragma unroll
        for (int j = 0; j < 4; ++j)
            sm[wv][64 * j + lane] = ex[j] * ixs - ey[j] * iys;
    }
    __syncthreads();
    #pragma unroll
    for (int cnt = 64; cnt >= 1; cnt >>= 1) {
        if (active && lane < cnt) {
            const int q = (cnt - 1) + lane;
            sm[wv][q] += sm[wv][2 * q + 1] + sm[wv][2 * q + 2];
        }
        __syncthreads();
    }
    float part = 0.f;
    if (active) {
        #pragma unroll
        for (int j = 0; j < 4; ++j) {
            const int e = 64 * j + lane;
            if (e < EDIM) part += fabsf(sm[wv][e] * w[e]);
        }
    }
    part = wave_reduce_sum(part);
    if (active && lane == 0) out[p] = -part;
}

extern "C" void kernel_launch(void* const* d_in, const int* in_sizes, int n_in,
                              void* d_out, int out_size, void* d_ws, size_t ws_size,
                              hipStream_t stream) {
    const int*   x   = (const int*)d_in[0];
    const int*   y   = (const int*)d_in[1];
    const float* emb = (const float*)d_in[2];
    const float* w   = (const float*)d_in[3];
    float* out = (float*)d_out;

    const int n_pairs = in_sizes[0];               // 4096 * 50 = 204800
    const int n_rows  = in_sizes[2] / EDIM;        // 100000

    const size_t need = (size_t)n_rows * EPAD * sizeof(unsigned short); // 51.2MB
    if (ws_size >= need) {
        unsigned short* tq = (unsigned short*)d_ws;
        const int g1 = min(2048, (n_rows + 3) / 4);
        const int g2 = min(2048, (n_pairs + 3) / 4);
        row_transform_b_kernel<<<g1, 256, 0, stream>>>(emb, w, tq, n_rows);
        pair_score_b_kernel<<<g2, 256, 0, stream>>>(x, y, tq, out, n_pairs);
    } else {
        treewe_score_kernel<<<(n_pairs + 3) / 4, 256, 0, stream>>>(
            x, y, emb, w, out, n_pairs);
    }
}